// Round 10
// baseline (319.700 us; speedup 1.0000x reference)
//
#include <hip/hip_runtime.h>
#include <math.h>

typedef float v2 __attribute__((ext_vector_type(2)));

#define SCALE 1073741824.0   // 2^30 fixed-point for deterministic atomic sum
#define NPIX 12582912.0      // 16*3*512*512
#define C1f 1e-4f
#define C2f 9e-4f

#define IMG_OFF 144          // floats per image segment in a slot (36 f4 chunks)
#define SLOT_STR 288         // floats per slot (imgA | imgB)
#define WAVE_STR 1152        // 4 slots per wave

struct Wts {
    float w[11];   // V-pass weights
    v2 hp[12];     // H-pass pair weights for element e=j+1: (w[j]|0, w[j-1]|0)
};

__device__ __forceinline__ v2 sp(float x) { v2 r; r.x = x; r.y = x; return r; }
__device__ __forceinline__ v2 f2(v2 a, v2 b, v2 c) {
    return __builtin_elementwise_fma(a, b, c);
}

// ---- global row load into parity-named regs (clamped rows, wave-local) ----
#define GLD(RP, RS, grow) do {                                              \
    int rc_ = (grow); rc_ = rc_ < 0 ? 0 : (rc_ > 511 ? 511 : rc_);          \
    RP = *(const float4*)(pgl + (size_t)rc_ * 512);                         \
    if (sec) RS = *(const float4*)(sgl + (size_t)rc_ * 512);                \
} while (0)

// ---- masked LDS stage of one row into slot SLW (literal) ----
#define SWRITE(SLW, RP, RS, grw) do {                                       \
    const float rm_ = ((unsigned)(grw) < 512u) ? 1.f : 0.f;                 \
    float4 o_;                                                              \
    o_.x = RP.x * (pm.x * rm_); o_.y = RP.y * (pm.y * rm_);                 \
    o_.z = RP.z * (pm.z * rm_); o_.w = RP.w * (pm.w * rm_);                 \
    *(float4*)(pwr + (SLW) * SLOT_STR) = o_;                                \
    if (sec) {                                                              \
        float4 s_;                                                          \
        s_.x = RS.x * (sm.x * rm_); s_.y = RS.y * (sm.y * rm_);             \
        s_.z = RS.z * (sm.z * rm_); s_.w = RS.w * (sm.w * rm_);             \
        *(float4*)(swr + (SLW) * SLOT_STR) = s_;                            \
    }                                                                       \
} while (0)

// ---- window chunk reads from slot SLR (literal) ----
#define HPLOAD(SLR) do {                                                    \
    const float* rp_ = rdp + (SLR) * SLOT_STR;                              \
    _Pragma("unroll") for (int k_ = 0; k_ < 7; ++k_) {                      \
        ca[k_] = *(const v2*)(rp_ + 2 * k_);                                \
        cb[k_] = *(const v2*)(rp_ + IMG_OFF + 2 * k_);                      \
    }                                                                       \
} while (0)

// ---- fused H-blur into ring slot PH (no intermediate arrays!) ----
#define HPMATH(PH) do {                                                     \
    v2 hS_ = sp(0.f), hD_ = sp(0.f), hP_ = sp(0.f), hM_ = sp(0.f);          \
    _Pragma("unroll") for (int j_ = 0; j_ < 12; ++j_) {                     \
        const int e_ = j_ + 1, ch_ = e_ >> 1;                               \
        const float xa_ = (e_ & 1) ? ca[ch_].y : ca[ch_].x;                 \
        const float xb_ = (e_ & 1) ? cb[ch_].y : cb[ch_].x;                 \
        const float u_ = xa_ + xb_, v_ = xa_ - xb_;                         \
        hS_ = f2(W.hp[j_], sp(u_), hS_);                                    \
        hD_ = f2(W.hp[j_], sp(v_), hD_);                                    \
        hP_ = f2(W.hp[j_], sp(u_ * u_), hP_);                               \
        hM_ = f2(W.hp[j_], sp(v_ * v_), hM_);                               \
    }                                                                       \
    rS[PH] = hS_; rD[PH] = hD_; rP[PH] = hP_; rM[PH] = hM_;                 \
} while (0)

// ---- V-blur + SSIM; window = ring slots (PH+1..PH+11)%12 ----
#define VOUTM(PH) do {                                                      \
    v2 S_ = sp(0.f), D_ = sp(0.f), P_ = sp(0.f), M_ = sp(0.f);              \
    _Pragma("unroll") for (int k_ = 0; k_ < 11; ++k_) {                     \
        const int q_ = ((PH) + 1 + k_) % 12;                                \
        const v2 wk_ = sp(W.w[k_]);                                         \
        S_ = f2(wk_, rS[q_], S_); D_ = f2(wk_, rD[q_], D_);                 \
        P_ = f2(wk_, rP[q_], P_); M_ = f2(wk_, rM[q_], M_);                 \
    }                                                                       \
    const v2 ss_ = S_ * S_, dd_ = D_ * D_;                                  \
    const v2 mu12_  = (ss_ - dd_) * sp(0.25f);                              \
    const v2 musq_  = (ss_ + dd_) * sp(0.5f);                               \
    const v2 sig12_ = (P_ - M_) * sp(0.25f) - mu12_;                        \
    const v2 sigsm_ = (P_ + M_) * sp(0.5f) - musq_;                         \
    const v2 num_ = (sp(2.f) * mu12_ + sp(C1f)) * (sp(2.f) * sig12_ + sp(C2f)); \
    const v2 den_ = (musq_ + sp(C1f)) * (sigsm_ + sp(C2f));                 \
    v2 r_;                                                                  \
    r_.x = __builtin_amdgcn_rcpf(den_.x);                                   \
    r_.y = __builtin_amdgcn_rcpf(den_.y);                                   \
    r_ = r_ * (sp(2.f) - den_ * r_);                                        \
    loc = f2(num_, r_, loc);                                                \
} while (0)

// ---- one step t: read slot t%4, stage slot (t+2)%4 (row t+2, loaded at ----
// ---- t-2), V-output (t>=11), H-push, issue load of row t+4. All waits ----
// ---- wave-local; sched_barrier bounds live ranges (anti-spill, R8).   ----
#define STEP(PH, SLR, SLW, PAR, scur, DOV) do {                             \
    HPLOAD(SLR);                                                            \
    if (PAR) { SWRITE(SLW, w1p, w1s, r0 - 3 + (scur)); }                    \
    else     { SWRITE(SLW, w0p, w0s, r0 - 3 + (scur)); }                    \
    if (DOV) VOUTM(PH);                                                     \
    HPMATH(PH);                                                             \
    if (PAR) { GLD(w1p, w1s, r0 - 1 + (scur)); }                            \
    else     { GLD(w0p, w0s, r0 - 1 + (scur)); }                            \
    __builtin_amdgcn_sched_barrier(0);                                      \
} while (0)

__global__ __launch_bounds__(256, 2) void ssim_main(
    const float* __restrict__ img1, const float* __restrict__ img2,
    unsigned long long* __restrict__ acc, Wts W)
{
    __shared__ float rowbuf[4 * WAVE_STR];     // 18432 B; 4 autonomous waves

    const int tid = threadIdx.x;
    const int lane = tid & 63;
    const int wv = tid >> 6;
    const int r0 = blockIdx.x * 32;            // 16 strips of 32 output rows
    const int plane = blockIdx.y;              // 48 planes
    const int c0w = wv * 128;                  // wave's column range

    const float* baseA = img1 + (size_t)plane * 262144;
    const float* baseB = img2 + (size_t)plane * 262144;

    float* wbase = rowbuf + wv * WAVE_STR;
    const float* rdp = wbase + 2 * lane + 2;   // window base (col c0w+2*lane-6)

    // staging roles: 72 f4 chunks cover [c0w-8, c0w+136) for both images
    const int pimg = (lane < 36) ? 0 : 1;
    const int pch  = (lane < 36) ? lane : lane - 36;
    const int pg0  = c0w - 8 + 4 * pch;
    const int pgc  = pg0 < 0 ? 0 : (pg0 > 508 ? 508 : pg0);
    const float* pgl = (pimg ? baseB : baseA) + pgc;
    float* pwr = wbase + pimg * IMG_OFF + 4 * pch;
    float4 pm;
    pm.x = (pg0 + 0 >= 0 && pg0 + 0 < 512) ? 1.f : 0.f;
    pm.y = (pg0 + 1 >= 0 && pg0 + 1 < 512) ? 1.f : 0.f;
    pm.z = (pg0 + 2 >= 0 && pg0 + 2 < 512) ? 1.f : 0.f;
    pm.w = (pg0 + 3 >= 0 && pg0 + 3 < 512) ? 1.f : 0.f;

    const bool sec = (lane < 8);               // img B chunks 28..35
    const int sch = 28 + lane;
    const int sg0 = c0w - 8 + 4 * sch;
    const int sgc = sg0 < 0 ? 0 : (sg0 > 508 ? 508 : sg0);
    const float* sgl = baseB + sgc;
    float* swr = wbase + IMG_OFF + 4 * sch;
    float4 sm;
    sm.x = (sg0 + 0 >= 0 && sg0 + 0 < 512) ? 1.f : 0.f;
    sm.y = (sg0 + 1 >= 0 && sg0 + 1 < 512) ? 1.f : 0.f;
    sm.z = (sg0 + 2 >= 0 && sg0 + 2 < 512) ? 1.f : 0.f;
    sm.w = (sg0 + 3 >= 0 && sg0 + 3 < 512) ? 1.f : 0.f;

    v2 rS[12], rD[12], rP[12], rM[12];         // 12-slot register ring
    v2 ca[7], cb[7];
    v2 loc = sp(0.f);
    float4 w0p, w0s, w1p, w1s;

    // ---- bootstrap: rows 0,1 -> slots 0,1; prefetch rows 2,3 ----
    GLD(w0p, w0s, r0 - 5);  SWRITE(0, w0p, w0s, r0 - 5);
    GLD(w1p, w1s, r0 - 4);  SWRITE(1, w1p, w1s, r0 - 4);
    GLD(w0p, w0s, r0 - 3);                     // row 2 (parity 0 consumes at t=0)
    GLD(w1p, w1s, r0 - 2);                     // row 3 (parity 1 consumes at t=1)
    __builtin_amdgcn_sched_barrier(0);

    // ---- prologue t=0..10: fill ring, no outputs ----
    STEP(0, 0, 2, 0, 0, 0);  STEP(1, 1, 3, 1, 1, 0);  STEP(2, 2, 0, 0, 2, 0);
    STEP(3, 3, 1, 1, 3, 0);  STEP(4, 0, 2, 0, 4, 0);  STEP(5, 1, 3, 1, 5, 0);
    STEP(6, 2, 0, 0, 6, 0);  STEP(7, 3, 1, 1, 7, 0);  STEP(8, 0, 2, 0, 8, 0);
    STEP(9, 1, 3, 1, 9, 0);  STEP(10, 2, 0, 0, 10, 0);

    // ---- main t=11..34: two 12-step bodies (phases period-12) ----
    for (int b = 0; b < 2; ++b) {
        const int sb = 11 + 12 * b;
        STEP(11, 3, 1, 1, sb + 0, 1);  STEP(0, 0, 2, 0, sb + 1, 1);
        STEP(1, 1, 3, 1, sb + 2, 1);   STEP(2, 2, 0, 0, sb + 3, 1);
        STEP(3, 3, 1, 1, sb + 4, 1);   STEP(4, 0, 2, 0, sb + 5, 1);
        STEP(5, 1, 3, 1, sb + 6, 1);   STEP(6, 2, 0, 0, sb + 7, 1);
        STEP(7, 3, 1, 1, sb + 8, 1);   STEP(8, 0, 2, 0, sb + 9, 1);
        STEP(9, 1, 3, 1, sb + 10, 1);  STEP(10, 2, 0, 0, sb + 11, 1);
    }
    // ---- tail t=35..42 ----
    STEP(11, 3, 1, 1, 35, 1);  STEP(0, 0, 2, 0, 36, 1);
    STEP(1, 1, 3, 1, 37, 1);   STEP(2, 2, 0, 0, 38, 1);
    STEP(3, 3, 1, 1, 39, 1);   STEP(4, 0, 2, 0, 40, 1);
    STEP(5, 1, 3, 1, 41, 1);   STEP(6, 2, 0, 0, 42, 1);

    // ---- per-wave reduction -> fixed-point global atomic (no barriers) ----
    float l = loc.x + loc.y;
#pragma unroll
    for (int o2 = 32; o2; o2 >>= 1)
        l += __shfl_down(l, o2, 64);
    if (lane == 0) {
        const unsigned long long q =
            (unsigned long long)__double2ll_rn((double)l * SCALE);
        atomicAdd(acc, q);
    }
}

__global__ void ssim_final(const unsigned long long* __restrict__ acc,
                           float* __restrict__ out)
{
    if (threadIdx.x == 0)
        out[0] = (float)((double)(*acc) * (1.0 / SCALE) / NPIX);
}

extern "C" void kernel_launch(void* const* d_in, const int* in_sizes, int n_in,
                              void* d_out, int out_size, void* d_ws, size_t ws_size,
                              hipStream_t stream) {
    const float* img1 = (const float*)d_in[0];
    const float* img2 = (const float*)d_in[1];
    float* out = (float*)d_out;
    unsigned long long* acc = (unsigned long long*)d_ws;

    double g[11], ssum = 0.0;
    for (int i = 0; i < 11; ++i) {
        const double d = (double)(i - 5);
        g[i] = exp(-(d * d) / 4.5);
        ssum += g[i];
    }
    Wts W;
    for (int i = 0; i < 11; ++i) W.w[i] = (float)(g[i] / ssum);
    for (int j = 0; j < 12; ++j) {
        v2 p;
        p.x = (j <= 10) ? W.w[j] : 0.f;      // out0 weight for element j+1
        p.y = (j >= 1) ? W.w[j - 1] : 0.f;   // out1 weight for element j+1
        W.hp[j] = p;
    }

    hipMemsetAsync(d_ws, 0, sizeof(unsigned long long), stream);
    ssim_main<<<dim3(16, 48), 256, 0, stream>>>(img1, img2, acc, W);
    ssim_final<<<1, 64, 0, stream>>>(acc, out);
}

// Round 11
// 317.783 us; speedup vs baseline: 1.0060x; 1.0060x over previous
//
#include <hip/hip_runtime.h>
#include <math.h>

typedef float v2 __attribute__((ext_vector_type(2)));

#define SCALE 1073741824.0   // 2^30 fixed-point for deterministic atomic sum
#define NPIX 12582912.0      // 16*3*512*512
#define C1f 1e-4f
#define C2f 9e-4f

struct Wts {
    float w[11];   // V-pass weights
    v2 hp[12];     // H-pass pair weights for element j: (w[j]|0, w[j-1]|0)
};

__device__ __forceinline__ v2 sp(float x) { v2 r; r.x = x; r.y = x; return r; }
__device__ __forceinline__ v2 f2(v2 a, v2 b, v2 c) {
    return __builtin_elementwise_fma(a, b, c);
}

// One 32-row strip for columns (c, c+1), c-5-EOFS divisible by 4.
// EOFS: element offset of window col c-5+j within the 4 f4 chunks
// (even-parity waves: chunks at c-8, EOFS=3; odd-parity: chunks at c-6, EOFS=1).
template<int EOFS>
__device__ __forceinline__ float do_strip(
    const float* __restrict__ baseA, const float* __restrict__ baseB,
    int c, int r0, const Wts& W)
{
    // 4 clamped, 16B-aligned chunk offsets per image
    int off[4];
#pragma unroll
    for (int k = 0; k < 4; ++k) {
        int o = c - 5 - EOFS + 4 * k;
        off[k] = o < 0 ? 0 : (o > 508 ? 508 : o);
    }
    // per-lane H weight pairs, zeroed where the element column is out of image
    v2 hpl[12];
#pragma unroll
    for (int j = 0; j < 12; ++j) {
        const int col = c - 5 + j;
        hpl[j] = (col >= 0 && col < 512) ? W.hp[j] : sp(0.f);
    }

    v2 rS[11], rD[11], rP[11], rM[11];         // ring: blurred u, v, u^2, v^2
    float4 a[4], b[4];                         // current row chunks
    v2 loc = sp(0.f);

    auto LOAD = [&](int gr) {                  // clamped, always-legal row load
        const int rc = gr < 0 ? 0 : (gr > 511 ? 511 : gr);
        const float* ra = baseA + rc * 512;
        const float* rb = baseB + rc * 512;
#pragma unroll
        for (int k = 0; k < 4; ++k) {
            a[k] = *(const float4*)(ra + off[k]);
            b[k] = *(const float4*)(rb + off[k]);
        }
    };
    auto HP = [&](int p, float m) {            // p compile-time at each site
        v2 hS = sp(0.f), hD = sp(0.f), hP = sp(0.f), hM = sp(0.f);
#pragma unroll
        for (int j = 0; j < 12; ++j) {
            const int e = j + EOFS;            // element col = c - 5 + j
            const int ch = e >> 2, cm = e & 3; // compile-time after unroll
            const float xa = cm == 0 ? a[ch].x : cm == 1 ? a[ch].y
                           : cm == 2 ? a[ch].z : a[ch].w;
            const float xb = cm == 0 ? b[ch].x : cm == 1 ? b[ch].y
                           : cm == 2 ? b[ch].z : b[ch].w;
            const float u = xa + xb, v = xa - xb;
            hS = f2(hpl[j], sp(u), hS);
            hD = f2(hpl[j], sp(v), hD);
            hP = f2(hpl[j], sp(u * u), hP);
            hM = f2(hpl[j], sp(v * v), hM);
        }
        const v2 mm = sp(m);                   // row-validity mask (0 or 1)
        rS[p] = hS * mm; rD[p] = hD * mm; rP[p] = hP * mm; rM[p] = hM * mm;
    };
    auto VOUT = [&](int p, float vm) {         // p compile-time at each site
        v2 S = sp(0.f), D = sp(0.f), P = sp(0.f), M = sp(0.f);
#pragma unroll
        for (int k = 0; k < 11; ++k) {
            const int q = (p + k) % 11;        // constant after unroll
            const v2 wk = sp(W.w[k]);
            S = f2(wk, rS[q], S);
            D = f2(wk, rD[q], D);
            P = f2(wk, rP[q], P);
            M = f2(wk, rM[q], M);
        }
        const v2 ss = S * S, dd = D * D;
        const v2 mu12  = (ss - dd) * sp(0.25f);
        const v2 musq  = (ss + dd) * sp(0.5f);
        const v2 sig12 = (P - M) * sp(0.25f) - mu12;
        const v2 sigsm = (P + M) * sp(0.5f) - musq;
        const v2 num = (sp(2.f) * mu12 + sp(C1f)) * (sp(2.f) * sig12 + sp(C2f));
        const v2 den = (musq + sp(C1f)) * (sigsm + sp(C2f));
        v2 r;
        r.x = __builtin_amdgcn_rcpf(den.x);
        r.y = __builtin_amdgcn_rcpf(den.y);
        r = r * (sp(2.f) - den * r);           // one NR step
        loc = f2(num * sp(vm), r, loc);        // vm: output-row validity mask
    };

    // ---- prologue: steps s=0..10 fill ring slots 0..10 (rows r0-5..r0+5) ----
#pragma unroll
    for (int s = 0; s < 11; ++s) {
        const int gr = r0 - 5 + s;
        LOAD(gr);
        const float m = (gr >= 0 && gr < 512) ? 1.f : 0.f;
        HP(s, m);
    }
    // ---- main: 2 x 11 steps + 9 tail + final VOUT (32 output rows) ----
    for (int bq = 0; bq < 2; ++bq) {
        const int sb = 11 * bq;
#pragma unroll
        for (int p = 0; p < 11; ++p) {
            const int gr = r0 + 6 + sb + p;
            LOAD(gr);
            const float vm = (r0 + sb + p < 512) ? 1.f : 0.f;
            VOUT(p, vm);
            const float m = (gr < 512) ? 1.f : 0.f;
            HP(p, m);
        }
    }
#pragma unroll
    for (int p = 0; p < 9; ++p) {              // steps 33..41, outputs 22..30
        const int gr = r0 + 28 + p;
        LOAD(gr);
        const float vm = (r0 + 22 + p < 512) ? 1.f : 0.f;
        VOUT(p, vm);
        const float m = (gr < 512) ? 1.f : 0.f;
        HP(p, m);
    }
    {                                          // output 31 (V only)
        const float vm = (r0 + 31 < 512) ? 1.f : 0.f;
        VOUT(9, vm);
    }
    return loc.x + loc.y;
}

__global__ void ssim_main(
    const float* __restrict__ img1, const float* __restrict__ img2,
    unsigned long long* __restrict__ acc, Wts W)
{
    __shared__ float red[4];
    const int tid = threadIdx.x;
    const int lane = tid & 63;
    const int wv = tid >> 6;
    const int r0 = blockIdx.x * 32;            // 16 strips of 32 output rows
    const int plane = blockIdx.y;              // 48 planes
    const int wpar = wv & 1;
    // stride-4 interleaved column pairs: chunk parity is wave-uniform
    const int c = (wv >> 1) * 256 + 4 * lane + 2 * wpar;

    const float* baseA = img1 + (size_t)plane * 262144;
    const float* baseB = img2 + (size_t)plane * 262144;

    float l = wpar ? do_strip<1>(baseA, baseB, c, r0, W)
                   : do_strip<3>(baseA, baseB, c, r0, W);

#pragma unroll
    for (int o2 = 32; o2; o2 >>= 1)
        l += __shfl_down(l, o2, 64);
    if (lane == 0) red[wv] = l;
    __syncthreads();
    if (tid == 0) {
        const float bs = red[0] + red[1] + red[2] + red[3];
        const unsigned long long q =
            (unsigned long long)__double2ll_rn((double)bs * SCALE);
        atomicAdd(acc, q);
    }
}

__global__ void ssim_final(const unsigned long long* __restrict__ acc,
                           float* __restrict__ out)
{
    if (threadIdx.x == 0)
        out[0] = (float)((double)(*acc) * (1.0 / SCALE) / NPIX);
}

extern "C" void kernel_launch(void* const* d_in, const int* in_sizes, int n_in,
                              void* d_out, int out_size, void* d_ws, size_t ws_size,
                              hipStream_t stream) {
    const float* img1 = (const float*)d_in[0];
    const float* img2 = (const float*)d_in[1];
    float* out = (float*)d_out;
    unsigned long long* acc = (unsigned long long*)d_ws;

    double g[11], ssum = 0.0;
    for (int i = 0; i < 11; ++i) {
        const double d = (double)(i - 5);
        g[i] = exp(-(d * d) / 4.5);
        ssum += g[i];
    }
    Wts W;
    for (int i = 0; i < 11; ++i) W.w[i] = (float)(g[i] / ssum);
    for (int j = 0; j < 12; ++j) {
        v2 p;
        p.x = (j <= 10) ? W.w[j] : 0.f;      // out0 weight for window col c-5+j
        p.y = (j >= 1) ? W.w[j - 1] : 0.f;   // out1 weight
        W.hp[j] = p;
    }

    hipMemsetAsync(d_ws, 0, sizeof(unsigned long long), stream);
    ssim_main<<<dim3(16, 48), 256, 0, stream>>>(img1, img2, acc, W);
    ssim_final<<<1, 64, 0, stream>>>(acc, out);
}

// Round 12
// 69.318 us; speedup vs baseline: 4.6121x; 4.5845x over previous
//
#include <hip/hip_runtime.h>
#include <math.h>

typedef float v2 __attribute__((ext_vector_type(2)));

#define SCALE 1073741824.0   // 2^30 fixed-point for deterministic atomic sum
#define NPIX 12582912.0      // 16*3*512*512
#define C1f 1e-4f
#define C2f 9e-4f

struct Wts {
    float w[11];   // V-pass weights
    v2 hp[12];     // H-pass pair weights for element j: (w[j]|0, w[j-1]|0)
};

__device__ __forceinline__ v2 sp(float x) { v2 r; r.x = x; r.y = x; return r; }
__device__ __forceinline__ v2 f2(v2 a, v2 b, v2 c) {
    return __builtin_elementwise_fma(a, b, c);
}

__global__ __launch_bounds__(256, 2) void ssim_main(
    const float* __restrict__ img1, const float* __restrict__ img2,
    unsigned long long* __restrict__ acc, Wts W)
{
    __shared__ float red[4];
    const int tid = threadIdx.x;
    const int lane = tid & 63;
    const int wv = tid >> 6;
    const int r0 = blockIdx.x * 33;            // 16 strips of 33 output rows
    const int plane = blockIdx.y;              // 48 planes
    const int c = wv * 128 + 2 * lane;         // this thread's columns c, c+1

    const float* baseA = img1 + (size_t)plane * 262144;
    const float* baseB = img2 + (size_t)plane * 262144;

    // per-lane clamped chunk offsets (7 x float2 chunks covering [c-6, c+8))
    int off[7];
#pragma unroll
    for (int k = 0; k < 7; ++k) {
        int o = c - 6 + 2 * k;
        off[k] = o < 0 ? 0 : (o > 510 ? 510 : o);
    }
    // per-lane H weight pairs, zeroed where the element column is out of image
    v2 hpl[12];
#pragma unroll
    for (int j = 0; j < 12; ++j) {
        const int col = c - 5 + j;
        hpl[j] = (col >= 0 && col < 512) ? W.hp[j] : sp(0.f);
    }

    v2 rS[11], rD[11], rP[11], rM[11];         // ring: blurred u, v, u^2, v^2
#pragma unroll
    for (int q = 0; q < 11; ++q) {             // zero ring: prologue VOUTs stay
        rS[q] = sp(0.f); rD[q] = sp(0.f);      // finite (den=C1*C2>0), masked
        rP[q] = sp(0.f); rM[q] = sp(0.f);
    }
    v2 a[7], b[7];
    v2 loc = sp(0.f);

    // ---- 44 steps as 4 x one 11-step body (~15 KB: fits 32 KB I$) --------
    // step t=11*it+p: load source row gr=r0-5+t, VOUT output row r0+t-11
    // (masked vm: t>=11 && row<512), push H-blur of row gr (masked m).
    for (int it = 0; it < 4; ++it) {
        const int t0 = 11 * it;
#pragma unroll
        for (int p = 0; p < 11; ++p) {
            const int t = t0 + p;
            const int gr = r0 - 5 + t;
            const int rc = gr < 0 ? 0 : (gr > 511 ? 511 : gr);
            const float* ra = baseA + rc * 512;
            const float* rb = baseB + rc * 512;
#pragma unroll
            for (int k = 0; k < 7; ++k) {      // issue loads first
                a[k] = *(const v2*)(ra + off[k]);
                b[k] = *(const v2*)(rb + off[k]);
            }
            // V-output (ring-only; overlaps the in-flight loads)
            {
                v2 S = sp(0.f), D = sp(0.f), P = sp(0.f), M = sp(0.f);
#pragma unroll
                for (int k = 0; k < 11; ++k) {
                    const int q = (p + k) % 11; // constant after unroll
                    const v2 wk = sp(W.w[k]);
                    S = f2(wk, rS[q], S);
                    D = f2(wk, rD[q], D);
                    P = f2(wk, rP[q], P);
                    M = f2(wk, rM[q], M);
                }
                const v2 ss = S * S, dd = D * D;
                const v2 mu12  = (ss - dd) * sp(0.25f);
                const v2 musq  = (ss + dd) * sp(0.5f);
                const v2 sig12 = (P - M) * sp(0.25f) - mu12;
                const v2 sigsm = (P + M) * sp(0.5f) - musq;
                const v2 num = (sp(2.f) * mu12 + sp(C1f)) *
                               (sp(2.f) * sig12 + sp(C2f));
                const v2 den = (musq + sp(C1f)) * (sigsm + sp(C2f));
                v2 r;
                r.x = __builtin_amdgcn_rcpf(den.x);
                r.y = __builtin_amdgcn_rcpf(den.y);
                r = r * (sp(2.f) - den * r);   // one NR step
                const float vm =
                    (t >= 11 && (r0 + t - 11) < 512) ? 1.f : 0.f;
                loc = f2(num * sp(vm), r, loc);
            }
            // H-push row gr into ring slot p
            {
                v2 hS = sp(0.f), hD = sp(0.f), hP = sp(0.f), hM = sp(0.f);
#pragma unroll
                for (int j = 0; j < 12; ++j) {
                    const int e = j + 1;       // element col = c - 6 + e
                    const float xa = (e & 1) ? a[e >> 1].y : a[e >> 1].x;
                    const float xb = (e & 1) ? b[e >> 1].y : b[e >> 1].x;
                    const float u = xa + xb, v = xa - xb;
                    hS = f2(hpl[j], sp(u), hS);
                    hD = f2(hpl[j], sp(v), hD);
                    hP = f2(hpl[j], sp(u * u), hP);
                    hM = f2(hpl[j], sp(v * v), hM);
                }
                const float m = ((unsigned)gr < 512u) ? 1.f : 0.f;
                const v2 mm = sp(m);
                rS[p] = hS * mm; rD[p] = hD * mm;
                rP[p] = hP * mm; rM[p] = hM * mm;
            }
            __builtin_amdgcn_sched_barrier(0); // fence: bounds live ranges
        }
    }

    // ---- reduction -> fixed-point global atomic ----
    float l = loc.x + loc.y;
#pragma unroll
    for (int o2 = 32; o2; o2 >>= 1)
        l += __shfl_down(l, o2, 64);
    if (lane == 0) red[wv] = l;
    __syncthreads();
    if (tid == 0) {
        const float bs = red[0] + red[1] + red[2] + red[3];
        const unsigned long long q =
            (unsigned long long)__double2ll_rn((double)bs * SCALE);
        atomicAdd(acc, q);
    }
}

__global__ void ssim_final(const unsigned long long* __restrict__ acc,
                           float* __restrict__ out)
{
    if (threadIdx.x == 0)
        out[0] = (float)((double)(*acc) * (1.0 / SCALE) / NPIX);
}

extern "C" void kernel_launch(void* const* d_in, const int* in_sizes, int n_in,
                              void* d_out, int out_size, void* d_ws, size_t ws_size,
                              hipStream_t stream) {
    const float* img1 = (const float*)d_in[0];
    const float* img2 = (const float*)d_in[1];
    float* out = (float*)d_out;
    unsigned long long* acc = (unsigned long long*)d_ws;

    double g[11], ssum = 0.0;
    for (int i = 0; i < 11; ++i) {
        const double d = (double)(i - 5);
        g[i] = exp(-(d * d) / 4.5);
        ssum += g[i];
    }
    Wts W;
    for (int i = 0; i < 11; ++i) W.w[i] = (float)(g[i] / ssum);
    for (int j = 0; j < 12; ++j) {
        v2 p;
        p.x = (j <= 10) ? W.w[j] : 0.f;      // out0 weight for window col c-5+j
        p.y = (j >= 1) ? W.w[j - 1] : 0.f;   // out1 weight
        W.hp[j] = p;
    }

    hipMemsetAsync(d_ws, 0, sizeof(unsigned long long), stream);
    ssim_main<<<dim3(16, 48), 256, 0, stream>>>(img1, img2, acc, W);
    ssim_final<<<1, 64, 0, stream>>>(acc, out);
}